// Round 1
// baseline (140.589 us; speedup 1.0000x reference)
//
#include <hip/hip_runtime.h>

// out[b,c,h,w] = clip(low*cc[b,c], 1e-8, 1) ^ (mask==0 ? g1[b,c] : g2[b,c])
// B=16, C=3, H=W=512. Total 12,582,912 elems. Pure streaming, 12 B/elem
// -> 151 MB -> ~24 us roofline at 6.3 TB/s achievable HBM BW.
//
// R1 changes vs baseline:
//  - grid capped at 2048 blocks (G11), 6x unrolled grid-stride loop:
//    6 independent float4/int4 load pairs in flight per thread (MLP),
//    12288 -> 2048 workgroup dispatches.
//  - nontemporal loads/stores: all three streams are touch-once (151 MB
//    >> 32 MB L2), nt avoids L2 displacement between the streams.

#define N_TOTAL  12582912
#define N_VEC    (N_TOTAL / 4)        // 3,145,728 float4 groups
#define NTHREADS 256
#define NBLOCKS  2048
#define STRIDE   (NBLOCKS * NTHREADS) // 524,288
#define NITER    (N_VEC / STRIDE)     // 6, exact fit (524288*6 = 3145728)

typedef float __attribute__((ext_vector_type(4))) f32x4;
typedef int   __attribute__((ext_vector_type(4))) i32x4;

__global__ __launch_bounds__(NTHREADS) void gamma_blend_kernel(
    const float* __restrict__ low,
    const float* __restrict__ g1,
    const float* __restrict__ g2,
    const float* __restrict__ cc,
    const int*   __restrict__ mask,
    float*       __restrict__ out)
{
    const int tid0 = blockIdx.x * NTHREADS + threadIdx.x;

    const f32x4* lp = reinterpret_cast<const f32x4*>(low);
    const i32x4* mp = reinterpret_cast<const i32x4*>(mask);
    f32x4*       op = reinterpret_cast<f32x4*>(out);

#pragma unroll
    for (int it = 0; it < NITER; ++it) {
        const int vid = tid0 + it * STRIDE;
        // 4 consecutive floats per vec index; plane size 2^18 elems
        // (2^16 float4s) -> all 4 in the same (b,c) plane.
        const int bc = vid >> 16;

        const f32x4 lv = __builtin_nontemporal_load(lp + vid);
        const i32x4 mv = __builtin_nontemporal_load(mp + vid);

        const float c_s = cc[bc];
        const float e1  = g1[bc];
        const float e2  = g2[bc];

        f32x4 ov;
#pragma unroll
        for (int j = 0; j < 4; ++j) {
            float x = fminf(fmaxf(lv[j] * c_s, 1e-8f), 1.0f);
            float g = (mv[j] == 0) ? e1 : e2;
            // v_log_f32 is log2, v_exp_f32 is exp2: x^g = exp2(g*log2(x))
            ov[j] = __builtin_amdgcn_exp2f(g * __builtin_amdgcn_logf(x));
        }

        __builtin_nontemporal_store(ov, op + vid);
    }
}

extern "C" void kernel_launch(void* const* d_in, const int* in_sizes, int n_in,
                              void* d_out, int out_size, void* d_ws, size_t ws_size,
                              hipStream_t stream) {
    // setup_inputs order: low_img, g1, g2, c, I_Mask
    const float* low  = (const float*)d_in[0];
    const float* g1   = (const float*)d_in[1];
    const float* g2   = (const float*)d_in[2];
    const float* cc   = (const float*)d_in[3];
    const int*   mask = (const int*)d_in[4];
    float* out = (float*)d_out;

    gamma_blend_kernel<<<NBLOCKS, NTHREADS, 0, stream>>>(low, g1, g2, cc, mask, out);
}